// Round 3
// baseline (162.034 us; speedup 1.0000x reference)
//
#include <hip/hip_runtime.h>

// FlatColorShader: out[b,h,w,:] = mean of 3 vertex colors of face pix_to_face[b,h,w,0],
// or 0 for background (-1).
//
// R3 = R2 with the nontemporal stores fixed to use a native clang vector type
// (ext_vector_type), since __builtin_nontemporal_store rejects HIP_vector_type.
//
//  - avg table stored as float4 (padded): 1 dwordx4 gather per pixel instead of
//    3 scalar dword gathers -> 3x fewer random addresses through the TA, each
//    gather touching exactly 1 cache line (16B aligned).
//  - 8 pixels/thread, all gathers issued before stores (ILP for latency hiding).
//  - nontemporal stores for the 98 MB output stream so it doesn't evict the
//    3.2 MB avg table from the per-XCD L2.

typedef float f32x4 __attribute__((ext_vector_type(4)));

__global__ void face_avg4_kernel(const float* __restrict__ verts,
                                 const int*   __restrict__ faces,
                                 float4*      __restrict__ avg4,
                                 int F) {
    int f = blockIdx.x * blockDim.x + threadIdx.x;
    if (f >= F) return;
    int i0 = faces[3 * f + 0];
    int i1 = faces[3 * f + 1];
    int i2 = faces[3 * f + 2];
    const float s = 1.0f / 3.0f;
    float r = (verts[3 * i0 + 0] + verts[3 * i1 + 0] + verts[3 * i2 + 0]) * s;
    float g = (verts[3 * i0 + 1] + verts[3 * i1 + 1] + verts[3 * i2 + 1]) * s;
    float b = (verts[3 * i0 + 2] + verts[3 * i1 + 2] + verts[3 * i2 + 2]) * s;
    avg4[f] = make_float4(r, g, b, 0.0f);
}

__global__ void shade_kernel(const int*    __restrict__ pix,
                             const float4* __restrict__ avg4,
                             float*        __restrict__ out,
                             int n_pix) {
    int t = blockIdx.x * blockDim.x + threadIdx.x;
    int p0 = t * 8;
    if (p0 >= n_pix) return;

    if (p0 + 7 < n_pix) {
        // 8 pixels: two int4 id loads (32B), 8 float4 gathers, 6 float4 stores (96B)
        const int4* pix4 = reinterpret_cast<const int4*>(pix);
        int4 ia = pix4[2 * t + 0];
        int4 ib = pix4[2 * t + 1];
        int id[8] = {ia.x, ia.y, ia.z, ia.w, ib.x, ib.y, ib.z, ib.w};

        float4 c[8];
#pragma unroll
        for (int j = 0; j < 8; ++j) {
            int f = id[j];
            c[j] = (f >= 0) ? avg4[f] : make_float4(0.f, 0.f, 0.f, 0.f);
        }

        // pack 8 x rgb = 24 floats = 6 float4; group byte offset = t*96 (16B aligned)
        f32x4* o = reinterpret_cast<f32x4*>(out) + t * 6;
        f32x4 s0 = {c[0].x, c[0].y, c[0].z, c[1].x};
        f32x4 s1 = {c[1].y, c[1].z, c[2].x, c[2].y};
        f32x4 s2 = {c[2].z, c[3].x, c[3].y, c[3].z};
        f32x4 s3 = {c[4].x, c[4].y, c[4].z, c[5].x};
        f32x4 s4 = {c[5].y, c[5].z, c[6].x, c[6].y};
        f32x4 s5 = {c[6].z, c[7].x, c[7].y, c[7].z};
        __builtin_nontemporal_store(s0, o + 0);
        __builtin_nontemporal_store(s1, o + 1);
        __builtin_nontemporal_store(s2, o + 2);
        __builtin_nontemporal_store(s3, o + 3);
        __builtin_nontemporal_store(s4, o + 4);
        __builtin_nontemporal_store(s5, o + 5);
    } else {
        // tail (n_pix % 8 != 0 only)
        for (int p = p0; p < n_pix; ++p) {
            int f = pix[p];
            float4 c = (f >= 0) ? avg4[f] : make_float4(0.f, 0.f, 0.f, 0.f);
            out[3 * p + 0] = c.x;
            out[3 * p + 1] = c.y;
            out[3 * p + 2] = c.z;
        }
    }
}

extern "C" void kernel_launch(void* const* d_in, const int* in_sizes, int n_in,
                              void* d_out, int out_size, void* d_ws, size_t ws_size,
                              hipStream_t stream) {
    const float* verts = (const float*)d_in[0];   // [V,3] f32
    const int*   faces = (const int*)d_in[1];     // [F,3] i32
    const int*   pix   = (const int*)d_in[2];     // [B,H,W,1] i32
    float*       out   = (float*)d_out;           // [B,H,W,3] f32
    float4*      avg4  = (float4*)d_ws;           // [F] float4 scratch (3.2 MB)

    int F     = in_sizes[1] / 3;
    int n_pix = in_sizes[2];

    {
        int threads = 256;
        int blocks  = (F + threads - 1) / threads;
        face_avg4_kernel<<<blocks, threads, 0, stream>>>(verts, faces, avg4, F);
    }
    {
        int n_groups = (n_pix + 7) / 8;
        int threads  = 256;
        int blocks   = (n_groups + threads - 1) / threads;
        shade_kernel<<<blocks, threads, 0, stream>>>(pix, avg4, out, n_pix);
    }
}

// Round 4
// 80.162 us; speedup vs baseline: 2.0213x; 2.0213x over previous
//
#include <hip/hip_runtime.h>

// FlatColorShader: out[b,h,w,:] = mean of 3 vertex colors of face pix_to_face[b,h,w,0],
// or 0 for background (-1).
//
// R4 = R3 WITHOUT nontemporal stores. R3's nt stores bypassed L2 write-combining:
// each 16B store became a partial-line HBM write -> WRITE_SIZE 98MB -> 275MB (2.8x),
// dur 68 -> 157us. Plain stores let L2 coalesce full lines.
//
// Kept from R2/R3:
//  - avg table stored as float4 (padded): 1 dwordx4 gather per pixel instead of
//    3 scalar dword gathers -> 3x fewer random addresses through the TA, each
//    gather touching exactly 1 cache line (16B aligned).
//  - 8 pixels/thread, all gathers issued before stores (ILP for latency hiding).

__global__ void face_avg4_kernel(const float* __restrict__ verts,
                                 const int*   __restrict__ faces,
                                 float4*      __restrict__ avg4,
                                 int F) {
    int f = blockIdx.x * blockDim.x + threadIdx.x;
    if (f >= F) return;
    int i0 = faces[3 * f + 0];
    int i1 = faces[3 * f + 1];
    int i2 = faces[3 * f + 2];
    const float s = 1.0f / 3.0f;
    float r = (verts[3 * i0 + 0] + verts[3 * i1 + 0] + verts[3 * i2 + 0]) * s;
    float g = (verts[3 * i0 + 1] + verts[3 * i1 + 1] + verts[3 * i2 + 1]) * s;
    float b = (verts[3 * i0 + 2] + verts[3 * i1 + 2] + verts[3 * i2 + 2]) * s;
    avg4[f] = make_float4(r, g, b, 0.0f);
}

__global__ void shade_kernel(const int*    __restrict__ pix,
                             const float4* __restrict__ avg4,
                             float*        __restrict__ out,
                             int n_pix) {
    int t = blockIdx.x * blockDim.x + threadIdx.x;
    int p0 = t * 8;
    if (p0 >= n_pix) return;

    if (p0 + 7 < n_pix) {
        // 8 pixels: two int4 id loads (32B), 8 float4 gathers, 6 float4 stores (96B)
        const int4* pix4 = reinterpret_cast<const int4*>(pix);
        int4 ia = pix4[2 * t + 0];
        int4 ib = pix4[2 * t + 1];
        int id[8] = {ia.x, ia.y, ia.z, ia.w, ib.x, ib.y, ib.z, ib.w};

        float4 c[8];
#pragma unroll
        for (int j = 0; j < 8; ++j) {
            int f = id[j];
            c[j] = (f >= 0) ? avg4[f] : make_float4(0.f, 0.f, 0.f, 0.f);
        }

        // pack 8 x rgb = 24 floats = 6 float4; group byte offset = t*96 (16B aligned)
        float4* o = reinterpret_cast<float4*>(out) + t * 6;
        o[0] = make_float4(c[0].x, c[0].y, c[0].z, c[1].x);
        o[1] = make_float4(c[1].y, c[1].z, c[2].x, c[2].y);
        o[2] = make_float4(c[2].z, c[3].x, c[3].y, c[3].z);
        o[3] = make_float4(c[4].x, c[4].y, c[4].z, c[5].x);
        o[4] = make_float4(c[5].y, c[5].z, c[6].x, c[6].y);
        o[5] = make_float4(c[6].z, c[7].x, c[7].y, c[7].z);
    } else {
        // tail (n_pix % 8 != 0 only)
        for (int p = p0; p < n_pix; ++p) {
            int f = pix[p];
            float4 c = (f >= 0) ? avg4[f] : make_float4(0.f, 0.f, 0.f, 0.f);
            out[3 * p + 0] = c.x;
            out[3 * p + 1] = c.y;
            out[3 * p + 2] = c.z;
        }
    }
}

extern "C" void kernel_launch(void* const* d_in, const int* in_sizes, int n_in,
                              void* d_out, int out_size, void* d_ws, size_t ws_size,
                              hipStream_t stream) {
    const float* verts = (const float*)d_in[0];   // [V,3] f32
    const int*   faces = (const int*)d_in[1];     // [F,3] i32
    const int*   pix   = (const int*)d_in[2];     // [B,H,W,1] i32
    float*       out   = (float*)d_out;           // [B,H,W,3] f32
    float4*      avg4  = (float4*)d_ws;           // [F] float4 scratch (3.2 MB)

    int F     = in_sizes[1] / 3;
    int n_pix = in_sizes[2];

    {
        int threads = 256;
        int blocks  = (F + threads - 1) / threads;
        face_avg4_kernel<<<blocks, threads, 0, stream>>>(verts, faces, avg4, F);
    }
    {
        int n_groups = (n_pix + 7) / 8;
        int threads  = 256;
        int blocks   = (n_groups + threads - 1) / threads;
        shade_kernel<<<blocks, threads, 0, stream>>>(pix, avg4, out, n_pix);
    }
}